// Round 11
// baseline (61.583 us; speedup 1.0000x reference)
//
#include <hip/hip_runtime.h>

typedef float v4f __attribute__((ext_vector_type(4)));

#define NPTS   4096
#define NB     8
#define QPT    16                  // queries per thread; 256*16 = all 4096 queries
#define TPB    256
#define CHUNK  32                  // points staged per block
#define NGRP   (CHUNK / 4)         // 8 groups of 4 points
#define NCHUNK (NPTS / CHUNK)      // 128
#define FINF   3.4e38f

__device__ __forceinline__ float min3f(float a, float b, float c) {
    float d;
    asm("v_min3_f32 %0, %1, %2, %3" : "=v"(d) : "v"(a), "v"(b), "v"(c));
    return d;
}

// One fused pass: each block = (chunk of 32 gts points, batch b), covering ALL
// 4096 pred queries (16/thread). Per pair compute d once; update BOTH the
// per-query col-min (registers) and the per-point row-min (registers + shfl
// butterfly per group). Row-mins are block-final -> stored directly; col-mins
// are per-chunk partials folded by the tail kernel.
__global__ __launch_bounds__(TPB, 4) void pair_kernel(const float* __restrict__ preds,
                                                      const float* __restrict__ gts,
                                                      float* __restrict__ colpart,
                                                      float* __restrict__ rowmins) {
    const int chunk = blockIdx.x;
    const int b     = blockIdx.y;
    const int tid   = threadIdx.x;
    const int lane  = tid & 63;
    const int wid   = tid >> 6;

    __shared__ float SX[CHUNK], SY[CHUNK], SZ[CHUNK], SW[CHUNK];
    __shared__ float rowpart[4][CHUNK];

    // ---- stage 32 gts points (SoA + |p|^2) ----
    if (tid < CHUNK) {
        const float* pb = gts + ((size_t)b * NPTS + chunk * CHUNK) * 3;
        float x = pb[tid * 3 + 0];
        float y = pb[tid * 3 + 1];
        float z = pb[tid * 3 + 2];
        SX[tid] = x; SY[tid] = y; SZ[tid] = z;
        SW[tid] = fmaf(x, x, fmaf(y, y, z * z));
    }

    // ---- 16 queries per thread (preds) ----
    const float* qb = preds + (size_t)b * NPTS * 3;
    float ax[QPT], ay[QPT], az[QPT], R[QPT], acc[QPT];
#pragma unroll
    for (int q = 0; q < QPT; ++q) {
        int   j  = q * TPB + tid;
        float qx = qb[j * 3 + 0];
        float qy = qb[j * 3 + 1];
        float qz = qb[j * 3 + 2];
        R[q]  = fmaf(qx, qx, fmaf(qy, qy, qz * qz));
        ax[q] = -2.0f * qx;
        ay[q] = -2.0f * qy;
        az[q] = -2.0f * qz;
        acc[q] = FINF;
    }
    __syncthreads();

    // ---- main loop: 4 points x 16 queries per group ----
#pragma unroll 2
    for (int g = 0; g < NGRP; ++g) {
        v4f X = *(const v4f*)&SX[4 * g];
        v4f Y = *(const v4f*)&SY[4 * g];
        v4f Z = *(const v4f*)&SZ[4 * g];
        v4f W = *(const v4f*)&SW[4 * g];
        float rm0 = FINF, rm1 = FINF, rm2 = FINF, rm3 = FINF;
#pragma unroll
        for (int q = 0; q < QPT; ++q) {
            float t0 = fmaf(X.x, ax[q], fmaf(Y.x, ay[q], fmaf(Z.x, az[q], W.x))) + R[q];
            float t1 = fmaf(X.y, ax[q], fmaf(Y.y, ay[q], fmaf(Z.y, az[q], W.y))) + R[q];
            float t2 = fmaf(X.z, ax[q], fmaf(Y.z, ay[q], fmaf(Z.z, az[q], W.z))) + R[q];
            float t3 = fmaf(X.w, ax[q], fmaf(Y.w, ay[q], fmaf(Z.w, az[q], W.w))) + R[q];
            acc[q] = min3f(t0, t1, min3f(t2, t3, acc[q]));   // col-min (this query)
            rm0 = fminf(rm0, t0);                            // row-min (these points)
            rm1 = fminf(rm1, t1);
            rm2 = fminf(rm2, t2);
            rm3 = fminf(rm3, t3);
        }
        // wave butterfly: min across 64 lanes (= across 1024 queries)
#pragma unroll
        for (int m = 1; m < 64; m <<= 1) {
            rm0 = fminf(rm0, __shfl_xor(rm0, m, 64));
            rm1 = fminf(rm1, __shfl_xor(rm1, m, 64));
            rm2 = fminf(rm2, __shfl_xor(rm2, m, 64));
            rm3 = fminf(rm3, __shfl_xor(rm3, m, 64));
        }
        if (lane == 0) {
            rowpart[wid][4 * g + 0] = rm0;
            rowpart[wid][4 * g + 1] = rm1;
            rowpart[wid][4 * g + 2] = rm2;
            rowpart[wid][4 * g + 3] = rm3;
        }
    }

    // ---- col partials: min over this chunk's 32 points, per query ----
    float* cp = colpart + ((size_t)b * NCHUNK + chunk) * NPTS;
#pragma unroll
    for (int q = 0; q < QPT; ++q) {
        cp[q * TPB + tid] = acc[q];
    }

    // ---- row-mins: combine 4 waves, block-final, store direct ----
    __syncthreads();
    if (tid < CHUNK) {
        float v = fminf(fminf(rowpart[0][tid], rowpart[1][tid]),
                        fminf(rowpart[2][tid], rowpart[3][tid]));
        rowmins[(size_t)b * NPTS + chunk * CHUNK + tid] = v;
    }
}

// Tail: thread s handles query s (fold 128 col partials + huber) AND point s
// (read final row-min + huber). Block partial-sum -> bp.
__global__ __launch_bounds__(256) void huber_kernel(const float* __restrict__ colpart,
                                                    const float* __restrict__ rowmins,
                                                    const float* __restrict__ cp_,
                                                    float* __restrict__ bp) {
    const int s = blockIdx.x * 256 + threadIdx.x;   // [0, NB*NPTS)
    const int b = s >> 12, m = s & (NPTS - 1);
    const float* p = colpart + ((size_t)b * NCHUNK) * NPTS + m;
    float cm = FINF;
#pragma unroll 4
    for (int c = 0; c < NCHUNK; ++c) cm = fminf(cm, p[(size_t)c * NPTS]);
    float rmv = rowmins[s];
    const float cc = cp_[0];
    float h1 = (cm  < cc) ? (0.5f * cm  * cm ) : fmaf(cc, cm,  -0.5f * cc * cc);
    float h2 = (rmv < cc) ? (0.5f * rmv * rmv) : fmaf(cc, rmv, -0.5f * cc * cc);
    float h = h1 + h2;
    for (int off = 32; off > 0; off >>= 1) h += __shfl_down(h, off, 64);
    __shared__ float ls[4];
    if ((threadIdx.x & 63) == 0) ls[threadIdx.x >> 6] = h;
    __syncthreads();
    if (threadIdx.x == 0) bp[blockIdx.x] = ls[0] + ls[1] + ls[2] + ls[3];
}

__global__ __launch_bounds__(256) void final_kernel(const float* __restrict__ bp,
                                                    float* __restrict__ out) {
    float a = bp[threadIdx.x];   // exactly 128 block partials, rest zero-padded
    for (int off = 32; off > 0; off >>= 1) a += __shfl_down(a, off, 64);
    __shared__ float ls[4];
    if ((threadIdx.x & 63) == 0) ls[threadIdx.x >> 6] = a;
    __syncthreads();
    if (threadIdx.x == 0) out[0] = ls[0] + ls[1] + ls[2] + ls[3];
}

__global__ __launch_bounds__(256) void zero_kernel(float* __restrict__ bp) {
    bp[threadIdx.x] = 0.0f;
}

extern "C" void kernel_launch(void* const* d_in, const int* in_sizes, int n_in,
                              void* d_out, int out_size, void* d_ws, size_t ws_size,
                              hipStream_t stream) {
    const float* preds = (const float*)d_in[0];  // [8, 4096, 3]
    const float* gts   = (const float*)d_in[1];  // [8, 4096, 3]
    const float* cp    = (const float*)d_in[2];  // [1]
    float* out = (float*)d_out;

    float* colpart = (float*)d_ws;                              // [8][128][4096] = 16 MB
    float* rowmins = colpart + (size_t)NB * NCHUNK * NPTS;      // [8][4096]
    float* bp      = rowmins + (size_t)NB * NPTS;               // [256]

    zero_kernel<<<1, 256, 0, stream>>>(bp);

    dim3 gm(NCHUNK, NB);   // (128, 8) = 1024 blocks
    pair_kernel<<<gm, TPB, 0, stream>>>(preds, gts, colpart, rowmins);

    huber_kernel<<<(NB * NPTS) / 256, 256, 0, stream>>>(colpart, rowmins, cp, bp);
    final_kernel<<<1, 256, 0, stream>>>(bp, out);
}

// Round 12
// 44.264 us; speedup vs baseline: 1.3913x; 1.3913x over previous
//
#include <hip/hip_runtime.h>

typedef float v4f __attribute__((ext_vector_type(4)));

#define NPTS   4096
#define NZ     16                  // B * 2 passes
#define QPT    8                   // queries per thread
#define TPB    256
#define QPB    (TPB * QPT)         // 2048
#define XB     (NPTS / QPB)        // 2
#define CHUNK  64                  // points staged per block (small => big grid)
#define NGRP   (CHUNK / 4)         // 16 groups of 4 points
#define NCHUNK (NPTS / CHUNK)      // 64

__device__ __forceinline__ float min3f(float a, float b, float c) {
    float d;
    asm("v_min3_f32 %0, %1, %2, %3" : "=v"(d) : "v"(a), "v"(b), "v"(c));
    return d;
}

// blockIdx: x = query slice (2), y = point chunk (64), z = b*2 + pass (16).
// 2048 blocks x 256 thr, __launch_bounds__(256,6): 6 blocks/CU resident
// (24 waves/CU, 6/SIMD) so VALU issue of some waves covers LDS waits of
// others — r2/r9/r10 were all grid-capped at 4 waves/SIMD and the two pipes
// serialized per-wave (invariant ~28us min phase).
__global__ __launch_bounds__(TPB, 6) void min_kernel(const float* __restrict__ preds,
                                                     const float* __restrict__ gts,
                                                     float* __restrict__ partial) {
    const int z    = blockIdx.z;
    const int b    = z >> 1;
    const int pass = z & 1;
    const int tid  = threadIdx.x;

    const float* pts = pass ? preds : gts;   // pass0: min over gts (per pred)
    const float* qrs = pass ? gts   : preds; // pass1: min over preds (per gt)

    __shared__ float SX[CHUNK], SY[CHUNK], SZ[CHUNK], SW[CHUNK];

    // ---- stage CHUNK points, transposed to 4-point SoA groups ----
    {
        const float* pb = pts + ((size_t)b * NPTS + blockIdx.y * CHUNK) * 3;
        if (tid < CHUNK) {
            float x  = pb[tid * 3 + 0];
            float y  = pb[tid * 3 + 1];
            float zz = pb[tid * 3 + 2];
            SX[tid] = x;
            SY[tid] = y;
            SZ[tid] = zz;
            SW[tid] = fmaf(x, x, fmaf(y, y, zz * zz));
        }
    }

    // ---- per-thread queries ----
    const float* qb    = qrs + (size_t)b * NPTS * 3;
    const int    jbase = blockIdx.x * QPB + tid;
    float ax[QPT], ay[QPT], az[QPT], R[QPT], acc[QPT];
#pragma unroll
    for (int q = 0; q < QPT; ++q) {
        int   j  = jbase + q * TPB;
        float qx = qb[j * 3 + 0];
        float qy = qb[j * 3 + 1];
        float qz = qb[j * 3 + 2];
        R[q]  = fmaf(qx, qx, fmaf(qy, qy, qz * qz));
        ax[q] = -2.0f * qx;
        ay[q] = -2.0f * qy;
        az[q] = -2.0f * qz;
        acc[q] = 3.4e38f;
    }
    __syncthreads();

    // ---- main loop: 4 points x QPT queries per group ----
    // per group: 4 broadcast ds_read_b128 + 8q x (12 fma + 2 min3) VALU.
#pragma unroll 2
    for (int g = 0; g < NGRP; ++g) {
        v4f X = *(const v4f*)&SX[4 * g];
        v4f Y = *(const v4f*)&SY[4 * g];
        v4f Z = *(const v4f*)&SZ[4 * g];
        v4f W = *(const v4f*)&SW[4 * g];
#pragma unroll
        for (int q = 0; q < QPT; ++q) {
            float t0 = fmaf(X.x, ax[q], fmaf(Y.x, ay[q], fmaf(Z.x, az[q], W.x)));
            float t1 = fmaf(X.y, ax[q], fmaf(Y.y, ay[q], fmaf(Z.y, az[q], W.y)));
            float t2 = fmaf(X.z, ax[q], fmaf(Y.z, ay[q], fmaf(Z.z, az[q], W.z)));
            float t3 = fmaf(X.w, ax[q], fmaf(Y.w, ay[q], fmaf(Z.w, az[q], W.w)));
            acc[q] = min3f(t0, t1, min3f(t2, t3, acc[q]));
        }
    }

    // ---- store per-(z,chunk) partial mins (unique slots, coalesced) ----
    float* dst = partial + ((size_t)z * NCHUNK + blockIdx.y) * NPTS;
#pragma unroll
    for (int q = 0; q < QPT; ++q) {
        dst[jbase + q * TPB] = R[q] + acc[q];
    }
}

// min over the NCHUNK partials per query, huber, block partial-sum.
// 256 blocks x 256 threads: consecutive threads touch consecutive j (coalesced).
__global__ __launch_bounds__(256) void huber_kernel(const float* __restrict__ partial,
                                                    const float* __restrict__ cp,
                                                    float* __restrict__ bp) {
    const int s = blockIdx.x * 256 + threadIdx.x;   // [0, NZ*NPTS)
    const int z = s >> 12, j = s & (NPTS - 1);
    const float* p = partial + (size_t)z * NCHUNK * NPTS + j;
    float m = 3.4e38f;
#pragma unroll 8
    for (int c = 0; c < NCHUNK; ++c) m = fminf(m, p[(size_t)c * NPTS]);
    const float cc = cp[0];
    float h = (m < cc) ? (0.5f * m * m) : fmaf(cc, m, -0.5f * cc * cc);
    for (int off = 32; off > 0; off >>= 1) h += __shfl_down(h, off, 64);
    __shared__ float ls[4];
    if ((threadIdx.x & 63) == 0) ls[threadIdx.x >> 6] = h;
    __syncthreads();
    if (threadIdx.x == 0) bp[blockIdx.x] = ls[0] + ls[1] + ls[2] + ls[3];
}

__global__ __launch_bounds__(256) void final_kernel(const float* __restrict__ bp,
                                                    float* __restrict__ out) {
    float a = bp[threadIdx.x];   // exactly 256 block partials
    for (int off = 32; off > 0; off >>= 1) a += __shfl_down(a, off, 64);
    __shared__ float ls[4];
    if ((threadIdx.x & 63) == 0) ls[threadIdx.x >> 6] = a;
    __syncthreads();
    if (threadIdx.x == 0) out[0] = ls[0] + ls[1] + ls[2] + ls[3];
}

extern "C" void kernel_launch(void* const* d_in, const int* in_sizes, int n_in,
                              void* d_out, int out_size, void* d_ws, size_t ws_size,
                              hipStream_t stream) {
    const float* preds = (const float*)d_in[0];  // [8, 4096, 3]
    const float* gts   = (const float*)d_in[1];  // [8, 4096, 3]
    const float* cp    = (const float*)d_in[2];  // [1]
    float* out = (float*)d_out;

    float* partial = (float*)d_ws;                           // [NZ][NCHUNK][NPTS] = 16 MB
    float* bp      = partial + (size_t)NZ * NCHUNK * NPTS;   // [256]

    dim3 gm(XB, NCHUNK, NZ);   // (2, 64, 16) = 2048 blocks
    min_kernel<<<gm, TPB, 0, stream>>>(preds, gts, partial);

    huber_kernel<<<(NZ * NPTS) / 256, 256, 0, stream>>>(partial, cp, bp);
    final_kernel<<<1, 256, 0, stream>>>(bp, out);
}